// Round 16
// baseline (219.572 us; speedup 1.0000x reference)
//
#include <hip/hip_runtime.h>
#include <hip/hip_fp8.h>

// ---------------------------------------------------------------------------
// GraphSAGE 2-layer encoder, MI355X.
//   out = leaky( mean_{j->i}(h_j) @ Wl + b + h_i @ Wr ), slope 0.5, x2 layers
// R16: restore counted-vmcnt pipeline in the R15 split-LDS GEMM (R15's
// rewrite accidentally drained next-tile loads with vmcnt(0) post-MFMA).
// Per-wave accounting: STAGE=2 vmem, epilogue=8 stores (exact via clamp).
// Steady top-of-iter wait: [L(cur)2 | S(prev)8 | L(next)2] -> vmcnt(10);
// last iter vmcnt(8). Mode1 keeps post-compute vmcnt(0)+WRITE_AR+lgkmcnt(0).
// Everything else identical to R15 (fp8 h0q only, packed 4B pairs,
// atomic-free parallel CSR chain, R10 agg).
// ---------------------------------------------------------------------------

typedef __attribute__((ext_vector_type(8))) short bf16x8;
typedef __attribute__((ext_vector_type(4))) float f32x4;

__device__ __forceinline__ float bf2f(unsigned short b) {
    union { unsigned u; float f; } x; x.u = ((unsigned)b) << 16; return x.f;
}
__device__ __forceinline__ short f2bf(float f) {
    union { float f; unsigned u; } x; x.f = f;
    unsigned r = x.u + 0x7fffu + ((x.u >> 16) & 1u);
    return (short)(r >> 16);
}
__device__ __forceinline__ unsigned char f2fp8(float f) {
    __hip_fp8_e4m3 q(f);
    return (unsigned char)q.__x;
}
__device__ __forceinline__ float fp82f(unsigned char b) {
    __hip_fp8_e4m3 q; q.__x = (__hip_fp8_storage_t)b;
    return (float)q;
}

// -------------------- bkhist + prep (fused, independent block ranges) ------
// histT layout: histT[b * 128 + c], b < 512 buckets, c < 128 chunks.

__global__ __launch_bounds__(512) void bkhist_prep_kernel(
    const int* __restrict__ ei, int* __restrict__ histT,
    int E, int NBK, int NCH, int CH,
    const float* __restrict__ x, short* __restrict__ xb,
    unsigned char* __restrict__ xq, float* __restrict__ xcopy,
    const float* __restrict__ Wl0, const float* __restrict__ Wr0,
    const float* __restrict__ Wl1, const float* __restrict__ Wr1,
    short* __restrict__ B1T, short* __restrict__ B2T, int total8) {
    if ((int)blockIdx.x < NCH) {
        __shared__ int h[512];
        int c = blockIdx.x;
        int base_e = c * CH;
        int nloc = E - base_e;
        if (nloc > CH) nloc = CH;
        h[threadIdx.x] = 0;
        __syncthreads();
        for (int t = threadIdx.x; t < nloc; t += 512)
            atomicAdd(&h[ei[E + base_e + t] >> 7], 1);
        __syncthreads();
        if ((int)threadIdx.x < NBK) histT[threadIdx.x * 128 + c] = h[threadIdx.x];
    } else {
        int gid = ((int)blockIdx.x - NCH) * 512 + threadIdx.x;
        if (gid < total8) {
            const float* p = x + (size_t)gid * 8;
            float4 v0 = *reinterpret_cast<const float4*>(p);
            float4 v1 = *reinterpret_cast<const float4*>(p + 4);
            bf16x8 t;
            t[0] = f2bf(v0.x); t[1] = f2bf(v0.y); t[2] = f2bf(v0.z); t[3] = f2bf(v0.w);
            t[4] = f2bf(v1.x); t[5] = f2bf(v1.y); t[6] = f2bf(v1.z); t[7] = f2bf(v1.w);
            *reinterpret_cast<bf16x8*>(xb + (size_t)gid * 8) = t;
            uchar4 q0, q1;
            q0.x = f2fp8(v0.x); q0.y = f2fp8(v0.y); q0.z = f2fp8(v0.z); q0.w = f2fp8(v0.w);
            q1.x = f2fp8(v1.x); q1.y = f2fp8(v1.y); q1.z = f2fp8(v1.z); q1.w = f2fp8(v1.w);
            *reinterpret_cast<uchar4*>(xq + (size_t)gid * 8) = q0;
            *reinterpret_cast<uchar4*>(xq + (size_t)gid * 8 + 4) = q1;
            *reinterpret_cast<float4*>(xcopy + (size_t)gid * 8) = v0;
            *reinterpret_cast<float4*>(xcopy + (size_t)gid * 8 + 4) = v1;
        } else {
            int idx = gid - total8;            // 0 .. 262143
            if (idx < 262144) {
                int sel = idx >> 17;
                int j = idx & 131071;
                int n = j >> 9;
                int k = j & 511;
                const float* Wl = sel ? Wl1 : Wl0;
                const float* Wr = sel ? Wr1 : Wr0;
                float v = (k < 256) ? Wl[k * 256 + n] : Wr[(k - 256) * 256 + n];
                (sel ? B2T : B1T)[j] = f2bf(v);
            }
        }
    }
}

// -------------------- scanA: one wave per bucket over chunks ---------------
__global__ __launch_bounds__(256) void scanA_kernel(
    int* __restrict__ histT, int* __restrict__ bktot, int NBK, int NCH) {
    int waveid = blockIdx.x * 4 + (threadIdx.x >> 6);
    int lane = threadIdx.x & 63;
    if (waveid >= NBK) return;
    int b = waveid;
    int v0 = (lane < NCH) ? histT[b * 128 + lane] : 0;
    int v1 = (64 + lane < NCH) ? histT[b * 128 + 64 + lane] : 0;
    int s0 = v0;
    #pragma unroll
    for (int d = 1; d < 64; d <<= 1) {
        int t = __shfl_up(s0, d, 64);
        if (lane >= d) s0 += t;
    }
    int t0 = __shfl(s0, 63, 64);
    int s1 = v1;
    #pragma unroll
    for (int d = 1; d < 64; d <<= 1) {
        int t = __shfl_up(s1, d, 64);
        if (lane >= d) s1 += t;
    }
    s1 += t0;
    if (lane < NCH) histT[b * 128 + lane] = s0 - v0;
    if (64 + lane < NCH) histT[b * 128 + 64 + lane] = s1 - v1;
    if (lane == 63) bktot[b] = __shfl(s1, 63, 64);
}

// -------------------- scanB: bucket totals -> bkoff (1 block) --------------
__global__ __launch_bounds__(512) void scanB_kernel(
    const int* __restrict__ bktot, int* __restrict__ bkoff,
    int* __restrict__ offs, int NBK, int N, int E) {
    __shared__ int sm[512];
    int tid = threadIdx.x;
    int v = (tid < NBK) ? bktot[tid] : 0;
    sm[tid] = v;
    __syncthreads();
    for (int off = 1; off < 512; off <<= 1) {
        int t = (tid >= off) ? sm[tid - off] : 0;
        __syncthreads();
        sm[tid] += t;
        __syncthreads();
    }
    if (tid < NBK) bkoff[tid] = sm[tid] - v;
    if (tid == 0) {
        bkoff[NBK] = E;
        offs[N] = E;
    }
}

// -------------------- binA: scatter packed pairs (no global atomics) -------
// pack = (dst & 127) << 25 | src   (requires N < 2^25)
__global__ __launch_bounds__(512) void binA_kernel(
    const int* __restrict__ ei, const int* __restrict__ histT,
    const int* __restrict__ bkoff, unsigned* __restrict__ pairs,
    int E, int NBK, int CH) {
    __shared__ int pos[512];
    int c = blockIdx.x;
    if ((int)threadIdx.x < NBK)
        pos[threadIdx.x] = histT[threadIdx.x * 128 + c] + bkoff[threadIdx.x];
    __syncthreads();
    int base_e = c * CH;
    int nloc = E - base_e;
    if (nloc > CH) nloc = CH;
    for (int t = threadIdx.x; t < nloc; t += 512) {
        int dst = ei[E + base_e + t];
        int src = ei[base_e + t];
        int p = atomicAdd(&pos[dst >> 7], 1);
        pairs[p] = ((unsigned)(dst & 127) << 25) | (unsigned)src;
    }
}

// -------------------- binB: per-node offs/invdeg + csr scatter -------------
__global__ __launch_bounds__(256) void binB_kernel(
    const unsigned* __restrict__ pairs, const int* __restrict__ bkoff,
    int* __restrict__ offs, float* __restrict__ invdeg,
    int* __restrict__ csr, int NBK, int N) {
    __shared__ int cnt[128];
    __shared__ int cur[128];
    int b = blockIdx.x;
    int t = threadIdx.x;
    if (t < 128) cnt[t] = 0;
    __syncthreads();
    int beg = bkoff[b];
    int end = bkoff[b + 1];
    for (int i = beg + t; i < end; i += 256)
        atomicAdd(&cnt[pairs[i] >> 25], 1);
    __syncthreads();
    if (t < 64) {
        int c0 = cnt[2 * t], c1 = cnt[2 * t + 1];
        int s = c0 + c1;
        int incl = s;
        #pragma unroll
        for (int d = 1; d < 64; d <<= 1) {
            int x = __shfl_up(incl, d, 64);
            if (t >= d) incl += x;
        }
        int excl = incl - s;
        cur[2 * t] = beg + excl;
        cur[2 * t + 1] = beg + excl + c0;
    }
    __syncthreads();
    if (t < 128) {
        int node = (b << 7) + t;
        if (node < N) {
            offs[node] = cur[t];
            invdeg[node] = 1.0f / (float)(cnt[t] > 0 ? cnt[t] : 1);
        }
    }
    __syncthreads();
    for (int i = beg + t; i < end; i += 256) {
        unsigned p = pairs[i];
        int pos = atomicAdd(&cur[p >> 25], 1);
        csr[pos] = (int)(p & 0x1FFFFFFu);
    }
}

// -------------------- mean aggregation (fp8 gather) --------------------
// One wave per node; lane t owns elements [4t,4t+4) (4B fp8/lane).
// 8 independent row loads in flight.
__global__ __launch_bounds__(256) void agg_kernel(
    const unsigned char* __restrict__ feat,
    const int* __restrict__ offs, const int* __restrict__ csr,
    const float* __restrict__ invdeg,
    short* __restrict__ outp, int N) {
    int wave = threadIdx.x >> 6;
    int lane = threadIdx.x & 63;
    int node = blockIdx.x * 4 + wave;
    if (node >= N) return;
    int beg = offs[node];
    int end = offs[node + 1];
    int c = lane * 4;

    float a[4][4];
    #pragma unroll
    for (int u = 0; u < 4; ++u)
        #pragma unroll
        for (int k = 0; k < 4; ++k) a[u][k] = 0.f;

    int deg = end - beg;
    int n8 = deg & ~7;
    for (int t = 0; t < n8; t += 8) {
        int s0 = csr[beg + t];     int s1 = csr[beg + t + 1];
        int s2 = csr[beg + t + 2]; int s3 = csr[beg + t + 3];
        int s4 = csr[beg + t + 4]; int s5 = csr[beg + t + 5];
        int s6 = csr[beg + t + 6]; int s7 = csr[beg + t + 7];
        unsigned u0 = *reinterpret_cast<const unsigned*>(feat + (size_t)s0 * 256 + c);
        unsigned u1 = *reinterpret_cast<const unsigned*>(feat + (size_t)s1 * 256 + c);
        unsigned u2 = *reinterpret_cast<const unsigned*>(feat + (size_t)s2 * 256 + c);
        unsigned u3 = *reinterpret_cast<const unsigned*>(feat + (size_t)s3 * 256 + c);
        unsigned u4 = *reinterpret_cast<const unsigned*>(feat + (size_t)s4 * 256 + c);
        unsigned u5 = *reinterpret_cast<const unsigned*>(feat + (size_t)s5 * 256 + c);
        unsigned u6 = *reinterpret_cast<const unsigned*>(feat + (size_t)s6 * 256 + c);
        unsigned u7 = *reinterpret_cast<const unsigned*>(feat + (size_t)s7 * 256 + c);
        #pragma unroll
        for (int k = 0; k < 4; ++k) a[0][k] += fp82f((u0 >> (8 * k)) & 0xff);
        #pragma unroll
        for (int k = 0; k < 4; ++k) a[1][k] += fp82f((u1 >> (8 * k)) & 0xff);
        #pragma unroll
        for (int k = 0; k < 4; ++k) a[2][k] += fp82f((u2 >> (8 * k)) & 0xff);
        #pragma unroll
        for (int k = 0; k < 4; ++k) a[3][k] += fp82f((u3 >> (8 * k)) & 0xff);
        #pragma unroll
        for (int k = 0; k < 4; ++k) a[0][k] += fp82f((u4 >> (8 * k)) & 0xff);
        #pragma unroll
        for (int k = 0; k < 4; ++k) a[1][k] += fp82f((u5 >> (8 * k)) & 0xff);
        #pragma unroll
        for (int k = 0; k < 4; ++k) a[2][k] += fp82f((u6 >> (8 * k)) & 0xff);
        #pragma unroll
        for (int k = 0; k < 4; ++k) a[3][k] += fp82f((u7 >> (8 * k)) & 0xff);
    }
    for (int e = beg + n8; e < end; ++e) {
        int s = csr[e];
        unsigned u = *reinterpret_cast<const unsigned*>(feat + (size_t)s * 256 + c);
        #pragma unroll
        for (int k = 0; k < 4; ++k) a[0][k] += fp82f((u >> (8 * k)) & 0xff);
    }
    float inv = invdeg[node];
    short4 o;
    o.x = f2bf((a[0][0] + a[1][0] + a[2][0] + a[3][0]) * inv);
    o.y = f2bf((a[0][1] + a[1][1] + a[2][1] + a[3][1]) * inv);
    o.z = f2bf((a[0][2] + a[1][2] + a[2][2] + a[3][2]) * inv);
    o.w = f2bf((a[0][3] + a[1][3] + a[2][3] + a[3][3]) * inv);
    *reinterpret_cast<short4*>(&outp[(size_t)node * 256 + c]) = o;
}

// -------------------- fused GEMM + bias + leaky --------------------
// C[M][256] = leaky( [AL | AR][M][512](bf16) @ B[512][256] + bias )
// Persistent 512 blocks, 1024 thr = 16 waves; wave w owns cols [w*16,+16).
// breg[16] = wave's B col-slice (K=512). 32-row tiles, split dbuf LDS
// ldsAL/ldsAR [2][32][256] (64KB). OUT_MODE 0: AR = xb bf16 via
// global_load_lds, writes fp8 h0q. OUT_MODE 1: AR = h0q fp8 reg-staged
// (uint2 -> exact fp8->bf16 -> swizzled ds_write_b128).
// Counted-vmcnt pipeline (stores count in vmcnt on CDNA): per-wave queue at
// top-of-iter wait = [L(cur)=2 | S(prev)=8 | L(next)=2] -> vmcnt(10); last
// iter vmcnt(8). Store count exact via row clamp (value-correct: staging
// clamps identically). Mode1 post-compute vmcnt(0) before WRITE_AR (needs
// next tile's nq; older stores done by then) + lgkmcnt(0) before barrier.
// Swizzle: LDS_X[r][j] = X[r][j ^ ((r&15)<<3)], within each 256-col half.
// C/D: lane l, reg r -> row (l>>4)*4+r, col l&15.
template <int OUT_MODE>
__global__ __launch_bounds__(1024, 4) void gemm_kernel(
    const short* __restrict__ AL, const void* __restrict__ ARv,
    const short* __restrict__ BT, const float* __restrict__ bias,
    float* __restrict__ Cout, unsigned char* __restrict__ Cq,
    int M, int ntiles) {
    __shared__ short ldsAL[2][32 * 256];
    __shared__ short ldsAR[2][32 * 256];
    int wave = threadIdx.x >> 6;        // 0..15
    int lane = threadIdx.x & 63;
    int l16 = lane & 15;
    int lhi = lane >> 4;
    int c0 = wave * 16;
    int rsub = lane >> 5;               // 0/1: which of the wave's 2 rows
    int jcol = (lane & 31) * 8;         // element column within row

    bf16x8 breg[16];
    #pragma unroll
    for (int kk = 0; kk < 16; ++kk)
        breg[kk] = *reinterpret_cast<const bf16x8*>(
            &BT[(size_t)(c0 + l16) * 512 + kk * 32 + lhi * 8]);
    float bc = bias[c0 + l16];

    const short* ARb = (const short*)ARv;
    const unsigned char* ARq = (const unsigned char*)ARv;
    uint2 nq;                           // staged fp8 data (mode 1)

    auto STAGE = [&](int tt, int buf) {
        int r = 2 * wave + rsub;
        int grow = tt * 32 + r;
        if (grow >= M) grow = M - 1;
        int swz = (r & 15) << 3;
        const short* srcA = AL + (size_t)grow * 256 + (jcol ^ swz);
        __builtin_amdgcn_global_load_lds(
            (const __attribute__((address_space(1))) unsigned int*)srcA,
            (__attribute__((address_space(3))) unsigned int*)
                &ldsAL[buf][2 * wave * 256], 16, 0, 0);
        if (OUT_MODE == 0) {
            const short* srcB = ARb + (size_t)grow * 256 + (jcol ^ swz);
            __builtin_amdgcn_global_load_lds(
                (const __attribute__((address_space(1))) unsigned int*)srcB,
                (__attribute__((address_space(3))) unsigned int*)
                    &ldsAR[buf][2 * wave * 256], 16, 0, 0);
        } else {
            nq = *reinterpret_cast<const uint2*>(
                ARq + (size_t)grow * 256 + (jcol ^ swz));
        }
    };
    auto WRITE_AR = [&](int buf) {      // mode 1: dequant + swizzled write
        int r = 2 * wave + rsub;
        bf16x8 w;
        #pragma unroll
        for (int k = 0; k < 4; ++k)
            w[k] = f2bf(fp82f((nq.x >> (8 * k)) & 0xff));
        #pragma unroll
        for (int k = 0; k < 4; ++k)
            w[4 + k] = f2bf(fp82f((nq.y >> (8 * k)) & 0xff));
        *reinterpret_cast<bf16x8*>(&ldsAR[buf][r * 256 + jcol]) = w;
    };

    int t = blockIdx.x;
    int stride = gridDim.x;
    if (t >= ntiles) return;

    // prologue: fill buffer 0 completely (also drains breg loads)
    STAGE(t, 0);
    asm volatile("s_waitcnt vmcnt(0)" ::: "memory");
    if (OUT_MODE == 1) {
        WRITE_AR(0);
        asm volatile("s_waitcnt lgkmcnt(0)" ::: "memory");
    }
    __builtin_amdgcn_s_barrier();
    __builtin_amdgcn_sched_barrier(0);

    int buf = 0;
    int it = 0;
    for (; t < ntiles; t += stride, ++it) {
        int tn = t + stride;
        bool havenext = (tn < ntiles);
        if (havenext) STAGE(tn, buf ^ 1);   // loads fly under this tile

        if (it > 0) {
            // wait only for THIS buffer's loads; prev stores + next loads
            // stay in flight.
            if (havenext) asm volatile("s_waitcnt vmcnt(10)" ::: "memory");
            else          asm volatile("s_waitcnt vmcnt(8)" ::: "memory");
            __builtin_amdgcn_s_barrier();
            __builtin_amdgcn_sched_barrier(0);
        }

        int row0 = t * 32;
        f32x4 acc[2];
        acc[0] = (f32x4){0.f, 0.f, 0.f, 0.f};
        acc[1] = (f32x4){0.f, 0.f, 0.f, 0.f};

        #pragma unroll
        for (int kk = 0; kk < 16; ++kk) {
            const short* lb = (kk < 8) ? &ldsAL[buf][0] : &ldsAR[buf][0];
            int kb = (kk & 7) * 32 + lhi * 8;
            int swz0 = (l16 & 15) << 3;     // same for row l16 and 16+l16
            bf16x8 a0 = *reinterpret_cast<const bf16x8*>(
                &lb[l16 * 256 + (kb ^ swz0)]);
            bf16x8 a1 = *reinterpret_cast<const bf16x8*>(
                &lb[(16 + l16) * 256 + (kb ^ swz0)]);
            acc[0] = __builtin_amdgcn_mfma_f32_16x16x32_bf16(
                a0, breg[kk], acc[0], 0, 0, 0);
            acc[1] = __builtin_amdgcn_mfma_f32_16x16x32_bf16(
                a1, breg[kk], acc[1], 0, 0, 0);
        }

        if (OUT_MODE == 1 && havenext) {
            // need next tile's nq (flew under compute); older stores done
            asm volatile("s_waitcnt vmcnt(0)" ::: "memory");
            WRITE_AR(buf ^ 1);
        }

        #pragma unroll
        for (int mt = 0; mt < 2; ++mt) {
            #pragma unroll
            for (int r = 0; r < 4; ++r) {
                int grow = row0 + mt * 16 + lhi * 4 + r;
                if (grow >= M) grow = M - 1;   // clamp: value-correct, keeps
                int gcol = c0 + l16;           // store count exact for vmcnt
                float v = acc[mt][r] + bc;
                v = (v >= 0.f) ? v : 0.5f * v;
                if (OUT_MODE == 0) {
                    Cq[(size_t)grow * 256 + gcol] = f2fp8(v);
                } else {
                    Cout[(size_t)grow * 256 + gcol] = v;
                }
            }
        }
        if (OUT_MODE == 1)
            asm volatile("s_waitcnt lgkmcnt(0)" ::: "memory");
        __builtin_amdgcn_s_barrier();       // buf reusable next iteration
        buf ^= 1;
    }
}

// -------------------- launch --------------------

extern "C" void kernel_launch(void* const* d_in, const int* in_sizes, int n_in,
                              void* d_out, int out_size, void* d_ws, size_t ws_size,
                              hipStream_t stream) {
    const float* x   = (const float*)d_in[0];
    const int*   ei  = (const int*)d_in[1];   // int64 in ref -> int32 from harness
    const float* Wl0 = (const float*)d_in[2];
    const float* bl0 = (const float*)d_in[3];
    const float* Wr0 = (const float*)d_in[4];
    const float* Wl1 = (const float*)d_in[5];
    const float* bl1 = (const float*)d_in[6];
    const float* Wr1 = (const float*)d_in[7];

    const int N = in_sizes[0] / 256;
    const int E = in_sizes[1] / 2;
    const int NBK = (N + 127) / 128;               // <= 512
    int CH = 8192;
    while ((E + CH - 1) / CH > 128) CH <<= 1;      // NCH <= 128
    const int NCH = (E + CH - 1) / CH;

    char* ws = (char*)d_ws;
    size_t o = 0;
    auto alloc = [&](size_t bytes) {
        size_t p = o;
        o = (o + bytes + 255) & ~(size_t)255;
        return p;
    };
    int*   offs   = (int*)  (ws + alloc((size_t)(N + 1) * 4));
    float* invdeg = (float*)(ws + alloc((size_t)N * 4));
    int*   histT  = (int*)  (ws + alloc((size_t)512 * 128 * 4));
    int*   bktot  = (int*)  (ws + alloc(512 * 4));
    int*   bkoff  = (int*)  (ws + alloc(((size_t)NBK + 1) * 4));
    unsigned* pairs = (unsigned*)(ws + alloc((size_t)E * 4));
    int*   csr    = (int*)  (ws + alloc((size_t)E * 4));
    short* xb     = (short*)(ws + alloc((size_t)N * 256 * 2));
    short* meanb  = (short*)(ws + alloc((size_t)N * 256 * 2));   // reused L0/L1
    unsigned char* xq  = (unsigned char*)(ws + alloc((size_t)N * 256));
    unsigned char* h0q = (unsigned char*)(ws + alloc((size_t)N * 256));
    short* B1T    = (short*)(ws + alloc(262144));
    short* B2T    = (short*)(ws + alloc(262144));

    int total8 = N * 32;
    int prep_blocks = (total8 + 262144 + 511) / 512;
    bkhist_prep_kernel<<<NCH + prep_blocks, 512, 0, stream>>>(
        ei, histT, E, NBK, NCH, CH,
        x, xb, xq, (float*)d_out + (size_t)N * 256,
        Wl0, Wr0, Wl1, Wr1, B1T, B2T, total8);
    scanA_kernel<<<(NBK + 3) / 4, 256, 0, stream>>>(histT, bktot, NBK, NCH);
    scanB_kernel<<<1, 512, 0, stream>>>(bktot, bkoff, offs, NBK, N, E);
    binA_kernel<<<NCH, 512, 0, stream>>>(ei, histT, bkoff, pairs, E, NBK, CH);
    binB_kernel<<<NBK, 256, 0, stream>>>(pairs, bkoff, offs, invdeg, csr, NBK, N);

    int ab = (N + 3) / 4;
    int ntiles = (N + 31) / 32;
    int gblocks = 512;
    // layer 0
    agg_kernel<<<ab, 256, 0, stream>>>(xq, offs, csr, invdeg, meanb, N);
    gemm_kernel<0><<<gblocks, 1024, 0, stream>>>(
        meanb, xb, B1T, bl0, nullptr, h0q, N, ntiles);
    // layer 1
    agg_kernel<<<ab, 256, 0, stream>>>(h0q, offs, csr, invdeg, meanb, N);
    gemm_kernel<1><<<gblocks, 1024, 0, stream>>>(
        meanb, h0q, B2T, bl1, (float*)d_out, nullptr, N, ntiles);
}

// Round 17
// 214.663 us; speedup vs baseline: 1.0229x; 1.0229x over previous
//
#include <hip/hip_runtime.h>
#include <hip/hip_fp8.h>

// ---------------------------------------------------------------------------
// GraphSAGE 2-layer encoder, MI355X.
//   out = leaky( mean_{j->i}(h_j) @ Wl + b + h_i @ Wr ), slope 0.5, x2 layers
// R17: xb (bf16 copy of x) eliminated. Both layers' root operand is fp8
// (xq / h0q), reg-staged: uint2 load -> exact fp8->bf16 dequant -> swizzled
// ds_write_b128. GEMM unified to the proven mode-1 single-barrier pipeline:
//   STAGE(next){AL global_load_lds + nq uint2} -> MFMA(cur) -> vmcnt(0)
//   -> WRITE_AR(next) -> epilogue stores -> lgkmcnt(0) -> s_barrier.
// Saves ~51MB traffic (prep xb write + gemm0 xb read). absmax budget:
// each fp8 path added ~+0.02 (0.0078->0.0215->0.041); expect ~0.06 < 0.108.
// CSR chain, agg, prep structure unchanged from R16.
// ---------------------------------------------------------------------------

typedef __attribute__((ext_vector_type(8))) short bf16x8;
typedef __attribute__((ext_vector_type(4))) float f32x4;

__device__ __forceinline__ short f2bf(float f) {
    union { float f; unsigned u; } x; x.f = f;
    unsigned r = x.u + 0x7fffu + ((x.u >> 16) & 1u);
    return (short)(r >> 16);
}
__device__ __forceinline__ unsigned char f2fp8(float f) {
    __hip_fp8_e4m3 q(f);
    return (unsigned char)q.__x;
}
__device__ __forceinline__ float fp82f(unsigned char b) {
    __hip_fp8_e4m3 q; q.__x = (__hip_fp8_storage_t)b;
    return (float)q;
}

// -------------------- bkhist + prep (fused, independent block ranges) ------
// histT layout: histT[b * 128 + c], b < 512 buckets, c < 128 chunks.

__global__ __launch_bounds__(512) void bkhist_prep_kernel(
    const int* __restrict__ ei, int* __restrict__ histT,
    int E, int NBK, int NCH, int CH,
    const float* __restrict__ x,
    unsigned char* __restrict__ xq, float* __restrict__ xcopy,
    const float* __restrict__ Wl0, const float* __restrict__ Wr0,
    const float* __restrict__ Wl1, const float* __restrict__ Wr1,
    short* __restrict__ B1T, short* __restrict__ B2T, int total8) {
    if ((int)blockIdx.x < NCH) {
        __shared__ int h[512];
        int c = blockIdx.x;
        int base_e = c * CH;
        int nloc = E - base_e;
        if (nloc > CH) nloc = CH;
        h[threadIdx.x] = 0;
        __syncthreads();
        for (int t = threadIdx.x; t < nloc; t += 512)
            atomicAdd(&h[ei[E + base_e + t] >> 7], 1);
        __syncthreads();
        if ((int)threadIdx.x < NBK) histT[threadIdx.x * 128 + c] = h[threadIdx.x];
    } else {
        int gid = ((int)blockIdx.x - NCH) * 512 + threadIdx.x;
        if (gid < total8) {
            const float* p = x + (size_t)gid * 8;
            float4 v0 = *reinterpret_cast<const float4*>(p);
            float4 v1 = *reinterpret_cast<const float4*>(p + 4);
            uchar4 q0, q1;
            q0.x = f2fp8(v0.x); q0.y = f2fp8(v0.y); q0.z = f2fp8(v0.z); q0.w = f2fp8(v0.w);
            q1.x = f2fp8(v1.x); q1.y = f2fp8(v1.y); q1.z = f2fp8(v1.z); q1.w = f2fp8(v1.w);
            *reinterpret_cast<uchar4*>(xq + (size_t)gid * 8) = q0;
            *reinterpret_cast<uchar4*>(xq + (size_t)gid * 8 + 4) = q1;
            *reinterpret_cast<float4*>(xcopy + (size_t)gid * 8) = v0;
            *reinterpret_cast<float4*>(xcopy + (size_t)gid * 8 + 4) = v1;
        } else {
            int idx = gid - total8;            // 0 .. 262143
            if (idx < 262144) {
                int sel = idx >> 17;
                int j = idx & 131071;
                int n = j >> 9;
                int k = j & 511;
                const float* Wl = sel ? Wl1 : Wl0;
                const float* Wr = sel ? Wr1 : Wr0;
                float v = (k < 256) ? Wl[k * 256 + n] : Wr[(k - 256) * 256 + n];
                (sel ? B2T : B1T)[j] = f2bf(v);
            }
        }
    }
}

// -------------------- scanA: one wave per bucket over chunks ---------------
__global__ __launch_bounds__(256) void scanA_kernel(
    int* __restrict__ histT, int* __restrict__ bktot, int NBK, int NCH) {
    int waveid = blockIdx.x * 4 + (threadIdx.x >> 6);
    int lane = threadIdx.x & 63;
    if (waveid >= NBK) return;
    int b = waveid;
    int v0 = (lane < NCH) ? histT[b * 128 + lane] : 0;
    int v1 = (64 + lane < NCH) ? histT[b * 128 + 64 + lane] : 0;
    int s0 = v0;
    #pragma unroll
    for (int d = 1; d < 64; d <<= 1) {
        int t = __shfl_up(s0, d, 64);
        if (lane >= d) s0 += t;
    }
    int t0 = __shfl(s0, 63, 64);
    int s1 = v1;
    #pragma unroll
    for (int d = 1; d < 64; d <<= 1) {
        int t = __shfl_up(s1, d, 64);
        if (lane >= d) s1 += t;
    }
    s1 += t0;
    if (lane < NCH) histT[b * 128 + lane] = s0 - v0;
    if (64 + lane < NCH) histT[b * 128 + 64 + lane] = s1 - v1;
    if (lane == 63) bktot[b] = __shfl(s1, 63, 64);
}

// -------------------- scanB: bucket totals -> bkoff (1 block) --------------
__global__ __launch_bounds__(512) void scanB_kernel(
    const int* __restrict__ bktot, int* __restrict__ bkoff,
    int* __restrict__ offs, int NBK, int N, int E) {
    __shared__ int sm[512];
    int tid = threadIdx.x;
    int v = (tid < NBK) ? bktot[tid] : 0;
    sm[tid] = v;
    __syncthreads();
    for (int off = 1; off < 512; off <<= 1) {
        int t = (tid >= off) ? sm[tid - off] : 0;
        __syncthreads();
        sm[tid] += t;
        __syncthreads();
    }
    if (tid < NBK) bkoff[tid] = sm[tid] - v;
    if (tid == 0) {
        bkoff[NBK] = E;
        offs[N] = E;
    }
}

// -------------------- binA: scatter packed pairs (no global atomics) -------
// pack = (dst & 127) << 25 | src   (requires N < 2^25)
__global__ __launch_bounds__(512) void binA_kernel(
    const int* __restrict__ ei, const int* __restrict__ histT,
    const int* __restrict__ bkoff, unsigned* __restrict__ pairs,
    int E, int NBK, int CH) {
    __shared__ int pos[512];
    int c = blockIdx.x;
    if ((int)threadIdx.x < NBK)
        pos[threadIdx.x] = histT[threadIdx.x * 128 + c] + bkoff[threadIdx.x];
    __syncthreads();
    int base_e = c * CH;
    int nloc = E - base_e;
    if (nloc > CH) nloc = CH;
    for (int t = threadIdx.x; t < nloc; t += 512) {
        int dst = ei[E + base_e + t];
        int src = ei[base_e + t];
        int p = atomicAdd(&pos[dst >> 7], 1);
        pairs[p] = ((unsigned)(dst & 127) << 25) | (unsigned)src;
    }
}

// -------------------- binB: per-node offs/invdeg + csr scatter -------------
__global__ __launch_bounds__(256) void binB_kernel(
    const unsigned* __restrict__ pairs, const int* __restrict__ bkoff,
    int* __restrict__ offs, float* __restrict__ invdeg,
    int* __restrict__ csr, int NBK, int N) {
    __shared__ int cnt[128];
    __shared__ int cur[128];
    int b = blockIdx.x;
    int t = threadIdx.x;
    if (t < 128) cnt[t] = 0;
    __syncthreads();
    int beg = bkoff[b];
    int end = bkoff[b + 1];
    for (int i = beg + t; i < end; i += 256)
        atomicAdd(&cnt[pairs[i] >> 25], 1);
    __syncthreads();
    if (t < 64) {
        int c0 = cnt[2 * t], c1 = cnt[2 * t + 1];
        int s = c0 + c1;
        int incl = s;
        #pragma unroll
        for (int d = 1; d < 64; d <<= 1) {
            int x = __shfl_up(incl, d, 64);
            if (t >= d) incl += x;
        }
        int excl = incl - s;
        cur[2 * t] = beg + excl;
        cur[2 * t + 1] = beg + excl + c0;
    }
    __syncthreads();
    if (t < 128) {
        int node = (b << 7) + t;
        if (node < N) {
            offs[node] = cur[t];
            invdeg[node] = 1.0f / (float)(cnt[t] > 0 ? cnt[t] : 1);
        }
    }
    __syncthreads();
    for (int i = beg + t; i < end; i += 256) {
        unsigned p = pairs[i];
        int pos = atomicAdd(&cur[p >> 25], 1);
        csr[pos] = (int)(p & 0x1FFFFFFu);
    }
}

// -------------------- mean aggregation (fp8 gather) --------------------
// One wave per node; lane t owns elements [4t,4t+4) (4B fp8/lane).
// 8 independent row loads in flight. (Best-measured variant; frozen.)
__global__ __launch_bounds__(256) void agg_kernel(
    const unsigned char* __restrict__ feat,
    const int* __restrict__ offs, const int* __restrict__ csr,
    const float* __restrict__ invdeg,
    short* __restrict__ outp, int N) {
    int wave = threadIdx.x >> 6;
    int lane = threadIdx.x & 63;
    int node = blockIdx.x * 4 + wave;
    if (node >= N) return;
    int beg = offs[node];
    int end = offs[node + 1];
    int c = lane * 4;

    float a[4][4];
    #pragma unroll
    for (int u = 0; u < 4; ++u)
        #pragma unroll
        for (int k = 0; k < 4; ++k) a[u][k] = 0.f;

    int deg = end - beg;
    int n8 = deg & ~7;
    for (int t = 0; t < n8; t += 8) {
        int s0 = csr[beg + t];     int s1 = csr[beg + t + 1];
        int s2 = csr[beg + t + 2]; int s3 = csr[beg + t + 3];
        int s4 = csr[beg + t + 4]; int s5 = csr[beg + t + 5];
        int s6 = csr[beg + t + 6]; int s7 = csr[beg + t + 7];
        unsigned u0 = *reinterpret_cast<const unsigned*>(feat + (size_t)s0 * 256 + c);
        unsigned u1 = *reinterpret_cast<const unsigned*>(feat + (size_t)s1 * 256 + c);
        unsigned u2 = *reinterpret_cast<const unsigned*>(feat + (size_t)s2 * 256 + c);
        unsigned u3 = *reinterpret_cast<const unsigned*>(feat + (size_t)s3 * 256 + c);
        unsigned u4 = *reinterpret_cast<const unsigned*>(feat + (size_t)s4 * 256 + c);
        unsigned u5 = *reinterpret_cast<const unsigned*>(feat + (size_t)s5 * 256 + c);
        unsigned u6 = *reinterpret_cast<const unsigned*>(feat + (size_t)s6 * 256 + c);
        unsigned u7 = *reinterpret_cast<const unsigned*>(feat + (size_t)s7 * 256 + c);
        #pragma unroll
        for (int k = 0; k < 4; ++k) a[0][k] += fp82f((u0 >> (8 * k)) & 0xff);
        #pragma unroll
        for (int k = 0; k < 4; ++k) a[1][k] += fp82f((u1 >> (8 * k)) & 0xff);
        #pragma unroll
        for (int k = 0; k < 4; ++k) a[2][k] += fp82f((u2 >> (8 * k)) & 0xff);
        #pragma unroll
        for (int k = 0; k < 4; ++k) a[3][k] += fp82f((u3 >> (8 * k)) & 0xff);
        #pragma unroll
        for (int k = 0; k < 4; ++k) a[0][k] += fp82f((u4 >> (8 * k)) & 0xff);
        #pragma unroll
        for (int k = 0; k < 4; ++k) a[1][k] += fp82f((u5 >> (8 * k)) & 0xff);
        #pragma unroll
        for (int k = 0; k < 4; ++k) a[2][k] += fp82f((u6 >> (8 * k)) & 0xff);
        #pragma unroll
        for (int k = 0; k < 4; ++k) a[3][k] += fp82f((u7 >> (8 * k)) & 0xff);
    }
    for (int e = beg + n8; e < end; ++e) {
        int s = csr[e];
        unsigned u = *reinterpret_cast<const unsigned*>(feat + (size_t)s * 256 + c);
        #pragma unroll
        for (int k = 0; k < 4; ++k) a[0][k] += fp82f((u >> (8 * k)) & 0xff);
    }
    float inv = invdeg[node];
    short4 o;
    o.x = f2bf((a[0][0] + a[1][0] + a[2][0] + a[3][0]) * inv);
    o.y = f2bf((a[0][1] + a[1][1] + a[2][1] + a[3][1]) * inv);
    o.z = f2bf((a[0][2] + a[1][2] + a[2][2] + a[3][2]) * inv);
    o.w = f2bf((a[0][3] + a[1][3] + a[2][3] + a[3][3]) * inv);
    *reinterpret_cast<short4*>(&outp[(size_t)node * 256 + c]) = o;
}

// -------------------- fused GEMM + bias + leaky (unified) --------------------
// C[M][256] = leaky( [AL | AR][M][512] @ B[512][256] + bias )
// Persistent 512 blocks, 1024 thr = 16 waves; wave w owns cols [w*16,+16).
// breg[16] = wave's B col-slice (K=512). 32-row tiles, split dbuf LDS
// ldsAL/ldsAR [2][32][256] (64KB). AL = meanb bf16 via global_load_lds.
// AR = fp8 (xq layer0 / h0q layer1), reg-staged: uint2 -> exact fp8->bf16 ->
// swizzled ds_write_b128 (per-lane LDS scatter legal for ds_write).
// Single-barrier pipeline (proven R16 mode-1 flow):
//   STAGE(next){AL gload + nq} -> MFMA(cur) -> vmcnt(0) [AL(next) in LDS,
//   nq(next) in reg, prev stores done; all covered by MFMA phase]
//   -> WRITE_AR(next) -> epilogue stores -> lgkmcnt(0) -> s_barrier.
// Swizzle: LDS_X[r][j] = X[r][j ^ ((r&15)<<3)], within each 256-col half.
// C/D: lane l, reg r -> row (l>>4)*4+r, col l&15. OOB rows clamp to M-1
// (value-correct: staging clamps identically).
template <int OUT_MODE>   // 0: fp8 h0q out, 1: f32 d_out
__global__ __launch_bounds__(1024, 4) void gemm_kernel(
    const short* __restrict__ AL, const unsigned char* __restrict__ ARq,
    const short* __restrict__ BT, const float* __restrict__ bias,
    float* __restrict__ Cout, unsigned char* __restrict__ Cq,
    int M, int ntiles) {
    __shared__ short ldsAL[2][32 * 256];
    __shared__ short ldsAR[2][32 * 256];
    int wave = threadIdx.x >> 6;        // 0..15
    int lane = threadIdx.x & 63;
    int l16 = lane & 15;
    int lhi = lane >> 4;
    int c0 = wave * 16;
    int rsub = lane >> 5;               // 0/1: which of the wave's 2 rows
    int jcol = (lane & 31) * 8;         // element column within row

    bf16x8 breg[16];
    #pragma unroll
    for (int kk = 0; kk < 16; ++kk)
        breg[kk] = *reinterpret_cast<const bf16x8*>(
            &BT[(size_t)(c0 + l16) * 512 + kk * 32 + lhi * 8]);
    float bc = bias[c0 + l16];

    uint2 nq;                           // staged fp8 root-row fragment

    auto STAGE = [&](int tt, int buf) {
        int r = 2 * wave + rsub;
        int grow = tt * 32 + r;
        if (grow >= M) grow = M - 1;
        int swz = (r & 15) << 3;
        const short* srcA = AL + (size_t)grow * 256 + (jcol ^ swz);
        __builtin_amdgcn_global_load_lds(
            (const __attribute__((address_space(1))) unsigned int*)srcA,
            (__attribute__((address_space(3))) unsigned int*)
                &ldsAL[buf][2 * wave * 256], 16, 0, 0);
        nq = *reinterpret_cast<const uint2*>(
            ARq + (size_t)grow * 256 + (jcol ^ swz));
    };
    auto WRITE_AR = [&](int buf) {      // dequant + swizzled LDS write
        int r = 2 * wave + rsub;
        bf16x8 w;
        #pragma unroll
        for (int k = 0; k < 4; ++k)
            w[k] = f2bf(fp82f((nq.x >> (8 * k)) & 0xff));
        #pragma unroll
        for (int k = 0; k < 4; ++k)
            w[4 + k] = f2bf(fp82f((nq.y >> (8 * k)) & 0xff));
        *reinterpret_cast<bf16x8*>(&ldsAR[buf][r * 256 + jcol]) = w;
    };

    int t = blockIdx.x;
    int stride = gridDim.x;
    if (t >= ntiles) return;

    // prologue: fill buffer 0 (also drains breg loads)
    STAGE(t, 0);
    asm volatile("s_waitcnt vmcnt(0)" ::: "memory");
    WRITE_AR(0);
    asm volatile("s_waitcnt lgkmcnt(0)" ::: "memory");
    __builtin_amdgcn_s_barrier();
    __builtin_amdgcn_sched_barrier(0);

    int buf = 0;
    for (; t < ntiles; t += stride) {
        int tn = t + stride;
        bool havenext = (tn < ntiles);
        if (havenext) STAGE(tn, buf ^ 1);   // loads fly under this tile

        int row0 = t * 32;
        f32x4 acc[2];
        acc[0] = (f32x4){0.f, 0.f, 0.f, 0.f};
        acc[1] = (f32x4){0.f, 0.f, 0.f, 0.f};

        #pragma unroll
        for (int kk = 0; kk < 16; ++kk) {
            const short* lb = (kk < 8) ? &ldsAL[buf][0] : &ldsAR[buf][0];
            int kb = (kk & 7) * 32 + lhi * 8;
            int swz0 = (l16 & 15) << 3;     // same for row l16 and 16+l16
            bf16x8 a0 = *reinterpret_cast<const bf16x8*>(
                &lb[l16 * 256 + (kb ^ swz0)]);
            bf16x8 a1 = *reinterpret_cast<const bf16x8*>(
                &lb[(16 + l16) * 256 + (kb ^ swz0)]);
            acc[0] = __builtin_amdgcn_mfma_f32_16x16x32_bf16(
                a0, breg[kk], acc[0], 0, 0, 0);
            acc[1] = __builtin_amdgcn_mfma_f32_16x16x32_bf16(
                a1, breg[kk], acc[1], 0, 0, 0);
        }

        // AL(next) landed in LDS, nq(next) in regs, prev stores done --
        // all had the full MFMA phase to complete.
        asm volatile("s_waitcnt vmcnt(0)" ::: "memory");
        if (havenext) WRITE_AR(buf ^ 1);

        #pragma unroll
        for (int mt = 0; mt < 2; ++mt) {
            #pragma unroll
            for (int r = 0; r < 4; ++r) {
                int grow = row0 + mt * 16 + lhi * 4 + r;
                if (grow >= M) grow = M - 1;   // clamp (value-correct)
                int gcol = c0 + l16;
                float v = acc[mt][r] + bc;
                v = (v >= 0.f) ? v : 0.5f * v;
                if (OUT_MODE == 0) {
                    Cq[(size_t)grow * 256 + gcol] = f2fp8(v);
                } else {
                    Cout[(size_t)grow * 256 + gcol] = v;
                }
            }
        }
        asm volatile("s_waitcnt lgkmcnt(0)" ::: "memory");
        __builtin_amdgcn_s_barrier();
        __builtin_amdgcn_sched_barrier(0);
        buf ^= 1;
    }
}

// -------------------- launch --------------------

extern "C" void kernel_launch(void* const* d_in, const int* in_sizes, int n_in,
                              void* d_out, int out_size, void* d_ws, size_t ws_size,
                              hipStream_t stream) {
    const float* x   = (const float*)d_in[0];
    const int*   ei  = (const int*)d_in[1];   // int64 in ref -> int32 from harness
    const float* Wl0 = (const float*)d_in[2];
    const float* bl0 = (const float*)d_in[3];
    const float* Wr0 = (const float*)d_in[4];
    const float* Wl1 = (const float*)d_in[5];
    const float* bl1 = (const float*)d_in[6];
    const float* Wr1 = (const float*)d_in[7];

    const int N = in_sizes[0] / 256;
    const int E = in_sizes[1] / 2;
    const int NBK = (N + 127) / 128;               // <= 512
    int CH = 8192;
    while ((E + CH - 1) / CH > 128) CH <<= 1;      // NCH <= 128
    const int NCH = (E + CH - 1) / CH;

    char* ws = (char*)d_ws;
    size_t o = 0;
    auto alloc = [&](size_t bytes) {
        size_t p = o;
        o = (o + bytes + 255) & ~(size_t)255;
        return p;
    };
    int*   offs   = (int*)  (ws + alloc((size_t)(N + 1) * 4));
    float* invdeg = (float*)(ws + alloc((size_t)N * 4));
    int*   histT  = (int*)  (ws + alloc((size_t)512 * 128 * 4));
    int*   bktot  = (int*)  (ws + alloc(512 * 4));
    int*   bkoff  = (int*)  (ws + alloc(((size_t)NBK + 1) * 4));
    unsigned* pairs = (unsigned*)(ws + alloc((size_t)E * 4));
    int*   csr    = (int*)  (ws + alloc((size_t)E * 4));
    short* meanb  = (short*)(ws + alloc((size_t)N * 256 * 2));   // reused L0/L1
    unsigned char* xq  = (unsigned char*)(ws + alloc((size_t)N * 256));
    unsigned char* h0q = (unsigned char*)(ws + alloc((size_t)N * 256));
    short* B1T    = (short*)(ws + alloc(262144));
    short* B2T    = (short*)(ws + alloc(262144));

    int total8 = N * 32;
    int prep_blocks = (total8 + 262144 + 511) / 512;
    bkhist_prep_kernel<<<NCH + prep_blocks, 512, 0, stream>>>(
        ei, histT, E, NBK, NCH, CH,
        x, xq, (float*)d_out + (size_t)N * 256,
        Wl0, Wr0, Wl1, Wr1, B1T, B2T, total8);
    scanA_kernel<<<(NBK + 3) / 4, 256, 0, stream>>>(histT, bktot, NBK, NCH);
    scanB_kernel<<<1, 512, 0, stream>>>(bktot, bkoff, offs, NBK, N, E);
    binA_kernel<<<NCH, 512, 0, stream>>>(ei, histT, bkoff, pairs, E, NBK, CH);
    binB_kernel<<<NBK, 256, 0, stream>>>(pairs, bkoff, offs, invdeg, csr, NBK, N);

    int ab = (N + 3) / 4;
    int ntiles = (N + 31) / 32;
    int gblocks = 512;
    // layer 0
    agg_kernel<<<ab, 256, 0, stream>>>(xq, offs, csr, invdeg, meanb, N);
    gemm_kernel<0><<<gblocks, 1024, 0, stream>>>(
        meanb, xq, B1T, bl0, nullptr, h0q, N, ntiles);
    // layer 1
    agg_kernel<<<ab, 256, 0, stream>>>(h0q, offs, csr, invdeg, meanb, N);
    gemm_kernel<1><<<gblocks, 1024, 0, stream>>>(
        meanb, h0q, B2T, bl1, (float*)d_out, nullptr, N, ntiles);
}

// Round 18
// 205.924 us; speedup vs baseline: 1.0663x; 1.0424x over previous
//
#include <hip/hip_runtime.h>
#include <hip/hip_fp8.h>

// ---------------------------------------------------------------------------
// GraphSAGE 2-layer encoder, MI355X.
//   out = leaky( mean_{j->i}(h_j) @ Wl + b + h_i @ Wr ), slope 0.5, x2 layers
// R18: (a) meanb is now fp8 -- agg writes fp8 means; gemm's AL half is
// reg-staged fp8 (uint2 -> exact fp8->bf16 -> swizzled ds_write), identical
// to the proven AR path. gemm has NO global_load_lds anymore. (b) scanB
// eliminated: fixed-capacity buckets (CAP = pow2 >= 4*E/NBK), bkoff[b]=b*CAP;
// binB writes explicit per-node end array oend (bucket gaps break the
// offs[node+1] convention). 8 launches total.
// ---------------------------------------------------------------------------

typedef __attribute__((ext_vector_type(8))) short bf16x8;
typedef __attribute__((ext_vector_type(4))) float f32x4;

__device__ __forceinline__ short f2bf(float f) {
    union { float f; unsigned u; } x; x.f = f;
    unsigned r = x.u + 0x7fffu + ((x.u >> 16) & 1u);
    return (short)(r >> 16);
}
__device__ __forceinline__ unsigned char f2fp8(float f) {
    __hip_fp8_e4m3 q(f);
    return (unsigned char)q.__x;
}
__device__ __forceinline__ float fp82f(unsigned char b) {
    __hip_fp8_e4m3 q; q.__x = (__hip_fp8_storage_t)b;
    return (float)q;
}

// -------------------- bkhist + prep (fused, independent block ranges) ------
// histT layout: histT[b * 128 + c], b < 512 buckets, c < 128 chunks.

__global__ __launch_bounds__(512) void bkhist_prep_kernel(
    const int* __restrict__ ei, int* __restrict__ histT,
    int E, int NBK, int NCH, int CH,
    const float* __restrict__ x,
    unsigned char* __restrict__ xq, float* __restrict__ xcopy,
    const float* __restrict__ Wl0, const float* __restrict__ Wr0,
    const float* __restrict__ Wl1, const float* __restrict__ Wr1,
    short* __restrict__ B1T, short* __restrict__ B2T, int total8) {
    if ((int)blockIdx.x < NCH) {
        __shared__ int h[512];
        int c = blockIdx.x;
        int base_e = c * CH;
        int nloc = E - base_e;
        if (nloc > CH) nloc = CH;
        h[threadIdx.x] = 0;
        __syncthreads();
        for (int t = threadIdx.x; t < nloc; t += 512)
            atomicAdd(&h[ei[E + base_e + t] >> 7], 1);
        __syncthreads();
        if ((int)threadIdx.x < NBK) histT[threadIdx.x * 128 + c] = h[threadIdx.x];
    } else {
        int gid = ((int)blockIdx.x - NCH) * 512 + threadIdx.x;
        if (gid < total8) {
            const float* p = x + (size_t)gid * 8;
            float4 v0 = *reinterpret_cast<const float4*>(p);
            float4 v1 = *reinterpret_cast<const float4*>(p + 4);
            uchar4 q0, q1;
            q0.x = f2fp8(v0.x); q0.y = f2fp8(v0.y); q0.z = f2fp8(v0.z); q0.w = f2fp8(v0.w);
            q1.x = f2fp8(v1.x); q1.y = f2fp8(v1.y); q1.z = f2fp8(v1.z); q1.w = f2fp8(v1.w);
            *reinterpret_cast<uchar4*>(xq + (size_t)gid * 8) = q0;
            *reinterpret_cast<uchar4*>(xq + (size_t)gid * 8 + 4) = q1;
            *reinterpret_cast<float4*>(xcopy + (size_t)gid * 8) = v0;
            *reinterpret_cast<float4*>(xcopy + (size_t)gid * 8 + 4) = v1;
        } else {
            int idx = gid - total8;            // 0 .. 262143
            if (idx < 262144) {
                int sel = idx >> 17;
                int j = idx & 131071;
                int n = j >> 9;
                int k = j & 511;
                const float* Wl = sel ? Wl1 : Wl0;
                const float* Wr = sel ? Wr1 : Wr0;
                float v = (k < 256) ? Wl[k * 256 + n] : Wr[(k - 256) * 256 + n];
                (sel ? B2T : B1T)[j] = f2bf(v);
            }
        }
    }
}

// -------------------- scanA: one wave per bucket over chunks ---------------
// histT[b][c] -> exclusive prefix within bucket b; bktot[b] = bucket total.
__global__ __launch_bounds__(256) void scanA_kernel(
    int* __restrict__ histT, int* __restrict__ bktot, int NBK, int NCH) {
    int waveid = blockIdx.x * 4 + (threadIdx.x >> 6);
    int lane = threadIdx.x & 63;
    if (waveid >= NBK) return;
    int b = waveid;
    int v0 = (lane < NCH) ? histT[b * 128 + lane] : 0;
    int v1 = (64 + lane < NCH) ? histT[b * 128 + 64 + lane] : 0;
    int s0 = v0;
    #pragma unroll
    for (int d = 1; d < 64; d <<= 1) {
        int t = __shfl_up(s0, d, 64);
        if (lane >= d) s0 += t;
    }
    int t0 = __shfl(s0, 63, 64);
    int s1 = v1;
    #pragma unroll
    for (int d = 1; d < 64; d <<= 1) {
        int t = __shfl_up(s1, d, 64);
        if (lane >= d) s1 += t;
    }
    s1 += t0;
    if (lane < NCH) histT[b * 128 + lane] = s0 - v0;
    if (64 + lane < NCH) histT[b * 128 + 64 + lane] = s1 - v1;
    if (lane == 63) bktot[b] = __shfl(s1, 63, 64);
}

// -------------------- binA: scatter packed pairs (no global atomics) -------
// Bucket b's region = [b*CAP, b*CAP + bktot[b]).  pack=(dst&127)<<25 | src.
__global__ __launch_bounds__(512) void binA_kernel(
    const int* __restrict__ ei, const int* __restrict__ histT,
    unsigned* __restrict__ pairs, int E, int NBK, int CH, int CAP) {
    __shared__ int pos[512];
    int c = blockIdx.x;
    if ((int)threadIdx.x < NBK)
        pos[threadIdx.x] = histT[threadIdx.x * 128 + c] + threadIdx.x * CAP;
    __syncthreads();
    int base_e = c * CH;
    int nloc = E - base_e;
    if (nloc > CH) nloc = CH;
    for (int t = threadIdx.x; t < nloc; t += 512) {
        int dst = ei[E + base_e + t];
        int src = ei[base_e + t];
        int p = atomicAdd(&pos[dst >> 7], 1);
        pairs[p] = ((unsigned)(dst & 127) << 25) | (unsigned)src;
    }
}

// -------------------- binB: per-node offs/oend/invdeg + csr scatter --------
__global__ __launch_bounds__(256) void binB_kernel(
    const unsigned* __restrict__ pairs, const int* __restrict__ bktot,
    int* __restrict__ offs, int* __restrict__ oend, float* __restrict__ invdeg,
    int* __restrict__ csr, int NBK, int N, int CAP) {
    __shared__ int cnt[128];
    __shared__ int cur[128];
    int b = blockIdx.x;
    int t = threadIdx.x;
    if (t < 128) cnt[t] = 0;
    __syncthreads();
    int beg = b * CAP;
    int end = beg + bktot[b];
    for (int i = beg + t; i < end; i += 256)
        atomicAdd(&cnt[pairs[i] >> 25], 1);
    __syncthreads();
    if (t < 64) {
        int c0 = cnt[2 * t], c1 = cnt[2 * t + 1];
        int s = c0 + c1;
        int incl = s;
        #pragma unroll
        for (int d = 1; d < 64; d <<= 1) {
            int x = __shfl_up(incl, d, 64);
            if (t >= d) incl += x;
        }
        int excl = incl - s;
        cur[2 * t] = beg + excl;
        cur[2 * t + 1] = beg + excl + c0;
    }
    __syncthreads();
    if (t < 128) {
        int node = (b << 7) + t;
        if (node < N) {
            offs[node] = cur[t];
            oend[node] = cur[t] + cnt[t];
            invdeg[node] = 1.0f / (float)(cnt[t] > 0 ? cnt[t] : 1);
        }
    }
    __syncthreads();
    for (int i = beg + t; i < end; i += 256) {
        unsigned p = pairs[i];
        int pos = atomicAdd(&cur[p >> 25], 1);
        csr[pos] = (int)(p & 0x1FFFFFFu);
    }
}

// -------------------- mean aggregation (fp8 gather, fp8 out) ---------------
// One wave per node; lane t owns elements [4t,4t+4) (4B fp8/lane).
// 8 independent row loads in flight. Output = fp8 mean (meanb).
__global__ __launch_bounds__(256) void agg_kernel(
    const unsigned char* __restrict__ feat,
    const int* __restrict__ offs, const int* __restrict__ oend,
    const int* __restrict__ csr, const float* __restrict__ invdeg,
    unsigned char* __restrict__ outp, int N) {
    int wave = threadIdx.x >> 6;
    int lane = threadIdx.x & 63;
    int node = blockIdx.x * 4 + wave;
    if (node >= N) return;
    int beg = offs[node];
    int end = oend[node];
    int c = lane * 4;

    float a[4][4];
    #pragma unroll
    for (int u = 0; u < 4; ++u)
        #pragma unroll
        for (int k = 0; k < 4; ++k) a[u][k] = 0.f;

    int deg = end - beg;
    int n8 = deg & ~7;
    for (int t = 0; t < n8; t += 8) {
        int s0 = csr[beg + t];     int s1 = csr[beg + t + 1];
        int s2 = csr[beg + t + 2]; int s3 = csr[beg + t + 3];
        int s4 = csr[beg + t + 4]; int s5 = csr[beg + t + 5];
        int s6 = csr[beg + t + 6]; int s7 = csr[beg + t + 7];
        unsigned u0 = *reinterpret_cast<const unsigned*>(feat + (size_t)s0 * 256 + c);
        unsigned u1 = *reinterpret_cast<const unsigned*>(feat + (size_t)s1 * 256 + c);
        unsigned u2 = *reinterpret_cast<const unsigned*>(feat + (size_t)s2 * 256 + c);
        unsigned u3 = *reinterpret_cast<const unsigned*>(feat + (size_t)s3 * 256 + c);
        unsigned u4 = *reinterpret_cast<const unsigned*>(feat + (size_t)s4 * 256 + c);
        unsigned u5 = *reinterpret_cast<const unsigned*>(feat + (size_t)s5 * 256 + c);
        unsigned u6 = *reinterpret_cast<const unsigned*>(feat + (size_t)s6 * 256 + c);
        unsigned u7 = *reinterpret_cast<const unsigned*>(feat + (size_t)s7 * 256 + c);
        #pragma unroll
        for (int k = 0; k < 4; ++k) a[0][k] += fp82f((u0 >> (8 * k)) & 0xff);
        #pragma unroll
        for (int k = 0; k < 4; ++k) a[1][k] += fp82f((u1 >> (8 * k)) & 0xff);
        #pragma unroll
        for (int k = 0; k < 4; ++k) a[2][k] += fp82f((u2 >> (8 * k)) & 0xff);
        #pragma unroll
        for (int k = 0; k < 4; ++k) a[3][k] += fp82f((u3 >> (8 * k)) & 0xff);
        #pragma unroll
        for (int k = 0; k < 4; ++k) a[0][k] += fp82f((u4 >> (8 * k)) & 0xff);
        #pragma unroll
        for (int k = 0; k < 4; ++k) a[1][k] += fp82f((u5 >> (8 * k)) & 0xff);
        #pragma unroll
        for (int k = 0; k < 4; ++k) a[2][k] += fp82f((u6 >> (8 * k)) & 0xff);
        #pragma unroll
        for (int k = 0; k < 4; ++k) a[3][k] += fp82f((u7 >> (8 * k)) & 0xff);
    }
    for (int e = beg + n8; e < end; ++e) {
        int s = csr[e];
        unsigned u = *reinterpret_cast<const unsigned*>(feat + (size_t)s * 256 + c);
        #pragma unroll
        for (int k = 0; k < 4; ++k) a[0][k] += fp82f((u >> (8 * k)) & 0xff);
    }
    float inv = invdeg[node];
    uchar4 o;
    o.x = f2fp8((a[0][0] + a[1][0] + a[2][0] + a[3][0]) * inv);
    o.y = f2fp8((a[0][1] + a[1][1] + a[2][1] + a[3][1]) * inv);
    o.z = f2fp8((a[0][2] + a[1][2] + a[2][2] + a[3][2]) * inv);
    o.w = f2fp8((a[0][3] + a[1][3] + a[2][3] + a[3][3]) * inv);
    *reinterpret_cast<uchar4*>(&outp[(size_t)node * 256 + c]) = o;
}

// -------------------- fused GEMM + bias + leaky (all-fp8 operands) ---------
// C[M][256] = leaky( [AL | AR][M][512] @ B[512][256] + bias )
// Persistent 512 blocks, 1024 thr = 16 waves; wave w owns cols [w*16,+16).
// breg[16] = wave's B col-slice (K=512). 32-row tiles, split dbuf LDS
// ldsAL/ldsAR [2][32][256] (64KB). BOTH halves fp8 reg-staged: uint2 load ->
// exact fp8->bf16 dequant -> swizzled ds_write_b128. No global_load_lds.
// Pipeline (proven single-barrier flow): STAGE(next){2 uint2} -> MFMA(cur)
// -> vmcnt(0) -> WRITE(next, both halves) -> epilogue stores -> lgkmcnt(0)
// -> s_barrier. Swizzle: LDS_X[r][j] = X[r][j ^ ((r&15)<<3)] per half.
// C/D: lane l, reg r -> row (l>>4)*4+r, col l&15. OOB rows clamp to M-1.
template <int OUT_MODE>   // 0: fp8 h0q out, 1: f32 d_out
__global__ __launch_bounds__(1024, 4) void gemm_kernel(
    const unsigned char* __restrict__ ALq, const unsigned char* __restrict__ ARq,
    const short* __restrict__ BT, const float* __restrict__ bias,
    float* __restrict__ Cout, unsigned char* __restrict__ Cq,
    int M, int ntiles) {
    __shared__ short ldsAL[2][32 * 256];
    __shared__ short ldsAR[2][32 * 256];
    int wave = threadIdx.x >> 6;        // 0..15
    int lane = threadIdx.x & 63;
    int l16 = lane & 15;
    int lhi = lane >> 4;
    int c0 = wave * 16;
    int rsub = lane >> 5;               // 0/1: which of the wave's 2 rows
    int jcol = (lane & 31) * 8;         // element column within row

    bf16x8 breg[16];
    #pragma unroll
    for (int kk = 0; kk < 16; ++kk)
        breg[kk] = *reinterpret_cast<const bf16x8*>(
            &BT[(size_t)(c0 + l16) * 512 + kk * 32 + lhi * 8]);
    float bc = bias[c0 + l16];

    uint2 nqL, nqR;                     // staged fp8 row fragments

    auto STAGE = [&](int tt) {
        int r = 2 * wave + rsub;
        int grow = tt * 32 + r;
        if (grow >= M) grow = M - 1;
        int off = jcol ^ ((r & 15) << 3);
        nqL = *reinterpret_cast<const uint2*>(ALq + (size_t)grow * 256 + off);
        nqR = *reinterpret_cast<const uint2*>(ARq + (size_t)grow * 256 + off);
    };
    auto WRITE = [&](int buf) {         // dequant + swizzled LDS writes
        int r = 2 * wave + rsub;
        bf16x8 wl, wr;
        #pragma unroll
        for (int k = 0; k < 4; ++k) {
            wl[k]     = f2bf(fp82f((nqL.x >> (8 * k)) & 0xff));
            wl[4 + k] = f2bf(fp82f((nqL.y >> (8 * k)) & 0xff));
            wr[k]     = f2bf(fp82f((nqR.x >> (8 * k)) & 0xff));
            wr[4 + k] = f2bf(fp82f((nqR.y >> (8 * k)) & 0xff));
        }
        *reinterpret_cast<bf16x8*>(&ldsAL[buf][r * 256 + jcol]) = wl;
        *reinterpret_cast<bf16x8*>(&ldsAR[buf][r * 256 + jcol]) = wr;
    };

    int t = blockIdx.x;
    int stride = gridDim.x;
    if (t >= ntiles) return;

    // prologue: fill buffer 0 (also drains breg loads)
    STAGE(t);
    asm volatile("s_waitcnt vmcnt(0)" ::: "memory");
    WRITE(0);
    asm volatile("s_waitcnt lgkmcnt(0)" ::: "memory");
    __builtin_amdgcn_s_barrier();
    __builtin_amdgcn_sched_barrier(0);

    int buf = 0;
    for (; t < ntiles; t += stride) {
        int tn = t + stride;
        bool havenext = (tn < ntiles);
        if (havenext) STAGE(tn);            // loads fly under this tile

        int row0 = t * 32;
        f32x4 acc[2];
        acc[0] = (f32x4){0.f, 0.f, 0.f, 0.f};
        acc[1] = (f32x4){0.f, 0.f, 0.f, 0.f};

        #pragma unroll
        for (int kk = 0; kk < 16; ++kk) {
            const short* lb = (kk < 8) ? &ldsAL[buf][0] : &ldsAR[buf][0];
            int kb = (kk & 7) * 32 + lhi * 8;
            int swz0 = (l16 & 15) << 3;     // same for row l16 and 16+l16
            bf16x8 a0 = *reinterpret_cast<const bf16x8*>(
                &lb[l16 * 256 + (kb ^ swz0)]);
            bf16x8 a1 = *reinterpret_cast<const bf16x8*>(
                &lb[(16 + l16) * 256 + (kb ^ swz0)]);
            acc[0] = __builtin_amdgcn_mfma_f32_16x16x32_bf16(
                a0, breg[kk], acc[0], 0, 0, 0);
            acc[1] = __builtin_amdgcn_mfma_f32_16x16x32_bf16(
                a1, breg[kk], acc[1], 0, 0, 0);
        }

        // nq(next) in regs, prev stores done -- covered by MFMA phase.
        asm volatile("s_waitcnt vmcnt(0)" ::: "memory");
        if (havenext) WRITE(buf ^ 1);

        #pragma unroll
        for (int mt = 0; mt < 2; ++mt) {
            #pragma unroll
            for (int r = 0; r < 4; ++r) {
                int grow = row0 + mt * 16 + lhi * 4 + r;
                if (grow >= M) grow = M - 1;   // clamp (value-correct)
                int gcol = c0 + l16;
                float v = acc[mt][r] + bc;
                v = (v >= 0.f) ? v : 0.5f * v;
                if (OUT_MODE == 0) {
                    Cq[(size_t)grow * 256 + gcol] = f2fp8(v);
                } else {
                    Cout[(size_t)grow * 256 + gcol] = v;
                }
            }
        }
        asm volatile("s_waitcnt lgkmcnt(0)" ::: "memory");
        __builtin_amdgcn_s_barrier();
        __builtin_amdgcn_sched_barrier(0);
        buf ^= 1;
    }
}

// -------------------- launch --------------------

extern "C" void kernel_launch(void* const* d_in, const int* in_sizes, int n_in,
                              void* d_out, int out_size, void* d_ws, size_t ws_size,
                              hipStream_t stream) {
    const float* x   = (const float*)d_in[0];
    const int*   ei  = (const int*)d_in[1];   // int64 in ref -> int32 from harness
    const float* Wl0 = (const float*)d_in[2];
    const float* bl0 = (const float*)d_in[3];
    const float* Wr0 = (const float*)d_in[4];
    const float* Wl1 = (const float*)d_in[5];
    const float* bl1 = (const float*)d_in[6];
    const float* Wr1 = (const float*)d_in[7];

    const int N = in_sizes[0] / 256;
    const int E = in_sizes[1] / 2;
    const int NBK = (N + 127) / 128;               // <= 512
    int CH = 8192;
    while ((E + CH - 1) / CH > 128) CH <<= 1;      // NCH <= 128
    const int NCH = (E + CH - 1) / CH;
    int CAP = 1;
    while (CAP < 4 * (E / NBK + 1)) CAP <<= 1;     // bucket capacity, pow2

    char* ws = (char*)d_ws;
    size_t o = 0;
    auto alloc = [&](size_t bytes) {
        size_t p = o;
        o = (o + bytes + 255) & ~(size_t)255;
        return p;
    };
    int*   offs   = (int*)  (ws + alloc((size_t)N * 4));
    int*   oendv  = (int*)  (ws + alloc((size_t)N * 4));
    float* invdeg = (float*)(ws + alloc((size_t)N * 4));
    int*   histT  = (int*)  (ws + alloc((size_t)512 * 128 * 4));
    int*   bktot  = (int*)  (ws + alloc(512 * 4));
    unsigned* pairs = (unsigned*)(ws + alloc((size_t)NBK * CAP * 4));
    int*   csr    = (int*)  (ws + alloc((size_t)NBK * CAP * 4));
    unsigned char* meanb = (unsigned char*)(ws + alloc((size_t)N * 256));
    unsigned char* xq    = (unsigned char*)(ws + alloc((size_t)N * 256));
    unsigned char* h0q   = (unsigned char*)(ws + alloc((size_t)N * 256));
    short* B1T    = (short*)(ws + alloc(262144));
    short* B2T    = (short*)(ws + alloc(262144));

    int total8 = N * 32;
    int prep_blocks = (total8 + 262144 + 511) / 512;
    bkhist_prep_kernel<<<NCH + prep_blocks, 512, 0, stream>>>(
        ei, histT, E, NBK, NCH, CH,
        x, xq, (float*)d_out + (size_t)N * 256,
        Wl0, Wr0, Wl1, Wr1, B1T, B2T, total8);
    scanA_kernel<<<(NBK + 3) / 4, 256, 0, stream>>>(histT, bktot, NBK, NCH);
    binA_kernel<<<NCH, 512, 0, stream>>>(ei, histT, pairs, E, NBK, CH, CAP);
    binB_kernel<<<NBK, 256, 0, stream>>>(pairs, bktot, offs, oendv, invdeg,
                                         csr, NBK, N, CAP);

    int ab = (N + 3) / 4;
    int ntiles = (N + 31) / 32;
    int gblocks = 512;
    // layer 0
    agg_kernel<<<ab, 256, 0, stream>>>(xq, offs, oendv, csr, invdeg, meanb, N);
    gemm_kernel<0><<<gblocks, 1024, 0, stream>>>(
        meanb, xq, B1T, bl0, nullptr, h0q, N, ntiles);
    // layer 1
    agg_kernel<<<ab, 256, 0, stream>>>(h0q, offs, oendv, csr, invdeg, meanb, N);
    gemm_kernel<1><<<gblocks, 1024, 0, stream>>>(
        meanb, h0q, B2T, bl1, (float*)d_out, nullptr, N, ntiles);
}